// Round 23
// baseline (270.113 us; speedup 1.0000x reference)
//
#include <hip/hip_runtime.h>
#include <hip/hip_bf16.h>

#define BATCH 32768
#define NELEM 65536   // 2 * BATCH

typedef unsigned short u16;
typedef unsigned int u32;
typedef __attribute__((ext_vector_type(8))) short bf16x8;
typedef __attribute__((ext_vector_type(4))) float f32x4;

__device__ __forceinline__ float bf2f(u16 u) {
    union { u32 u; float f; } c; c.u = ((u32)u) << 16; return c.f;
}
__device__ __forceinline__ u16 f2bf(float f) {
    union { float f; u32 u; } c; c.f = f;
    u32 x = c.u;
    u32 r = (x + 0x7fffu + ((x >> 16) & 1u)) >> 16;  // RNE
    return (u16)r;
}

// ---------------- K0: weight prep ---------------------------------------
__global__ __launch_bounds__(256) void k0_prep(const float* __restrict__ pw,
        const float* __restrict__ w2, const float* __restrict__ w3,
        const float* __restrict__ h2w, const float* __restrict__ h1w,
        const float* __restrict__ w1,
        u16* __restrict__ pwT, u16* __restrict__ w2r, u16* __restrict__ w3r,
        u16* __restrict__ h2hi, u16* __restrict__ h2lo,
        u16* __restrict__ h1hi, u16* __restrict__ h1lo,
        u16* __restrict__ w1hi, u16* __restrict__ w1lo) {
    int idx = blockIdx.x * 256 + threadIdx.x;
    if (idx < 38912) {
        int j = idx / 608, kk = idx - j * 608;
        float v = 0.f;
        if (kk < 576) {
            int p = kk >> 6, oc = kk & 63;
            v = pw[j * 578 + oc * 9 + p];
        } else if (kk < 578) {
            v = pw[j * 578 + kk];
        }
        pwT[idx] = f2bf(v);
    } else if (idx < 40960) {
        int i = idx - 38912;
        int oc = i >> 6, rem = i & 63, tap = rem >> 4, ic = rem & 15;
        w2r[i] = f2bf(w2[oc * 64 + ic * 4 + tap]);
    } else if (idx < 49152) {
        int i = idx - 40960;
        int oc = i >> 7, rem = i & 127, tap = rem >> 5, ic = rem & 31;
        w3r[i] = f2bf(w3[oc * 128 + ic * 4 + tap]);
    } else if (idx < 65536) {
        int i = idx - 49152;
        float v = h2w[i];
        u16 hi = f2bf(v);
        h2hi[i] = hi;
        h2lo[i] = f2bf(v - bf2f(hi));
    } else if (idx < 86016) {
        int i = idx - 65536;
        int j = i / 160, k = i - j * 160;
        float v = (k < 132) ? h1w[j * 132 + k] : 0.f;
        u16 hi = f2bf(v);
        h1hi[i] = hi;
        h1lo[i] = f2bf(v - bf2f(hi));
    } else if (idx < 86528) {
        int i = idx - 86016;               // [oc16][k32]
        int oc = i >> 5, k = i & 31;
        int ky = k >> 4, kx = (k >> 3) & 1, c = k & 7;
        float v = (c < 3) ? w1[oc * 12 + c * 4 + ky * 2 + kx] : 0.f;
        u16 hi = f2bf(v);
        w1hi[i] = hi;
        w1lo[i] = f2bf(v - bf2f(hi));
    }
}

__device__ __forceinline__ void split8(const float* __restrict__ x,
                                       bf16x8& hi, bf16x8& lo) {
    #pragma unroll
    for (int j = 0; j < 8; ++j) {
        u16 h = f2bf(x[j]);
        hi[j] = (short)h;
        lo[j] = (short)f2bf(x[j] - bf2f(h));
    }
}

// ---------------- KALL: whole network, one block = 16 batch rows --------
// LDS restructured for 4 blocks/CU (38528 B): frame staged in 8 passes of
// 4 elems; conv3+proj per 16-elem half (featL halved); combL gets its own
// region (no longer overlays live p2L). All arithmetic identical to R21.
// LDS map (u16): p2L [0,4096) | combL [4096,8192) | p1L [8192,16384)
// featL [8192,18432) (after B) | frL [16384,19008) | hL over featL (E-H)
__global__ __launch_bounds__(256) void kall(const int* __restrict__ frame,
        const u16* __restrict__ w1hi, const u16* __restrict__ w1lo,
        const float* __restrict__ b1,
        const u16* __restrict__ w2r, const float* __restrict__ b2,
        const u16* __restrict__ w3r, const float* __restrict__ b3,
        const int* __restrict__ ccol, const int* __restrict__ cobj,
        const u16* __restrict__ pwT, const float* __restrict__ pb,
        const u16* __restrict__ h1hi, const u16* __restrict__ h1lo,
        const float* __restrict__ h1b,
        const float* __restrict__ lng, const float* __restrict__ lnb,
        const u16* __restrict__ h2hi, const u16* __restrict__ h2lo,
        const float* __restrict__ h2b,
        const float* __restrict__ h3w, const float* __restrict__ h3b,
        float* __restrict__ out) {
    __shared__ u16 lds[19008];     // 38016 B
    __shared__ float4 fdirL[32];   // 512 B
    u16* p2L     = lds;                    // [0,4096)
    float* combL = (float*)(lds + 4096);   // 2048 floats
    u16* p1L     = lds + 8192;             // [8192,16384)
    u16* frL     = lds + 16384;            // 4*656 = 2624
    u16* featL   = lds + 8192;             // 16*640 = 10240 (overlay, after B)
    float* hL    = (float*)(lds + 8192);   // 16*132 floats (overlay, after D)
    int t = threadIdx.x;
    int l = t & 63;
    int wv = t >> 6;
    int col = l & 15;
    int kg = l >> 4;
    int b0 = blockIdx.x * 16;

    // zero frL (pad ring persists; interior overwritten each pass)
    #pragma unroll
    for (int i = 0; i < 2; ++i) {
        int o = i * 256 + t;
        if (o < 328) *(uint4*)(frL + o * 8) = make_uint4(0u, 0u, 0u, 0u);
    }

    // ---- phase A: conv1+relu+pool, 8 passes of 4 elems + dir scan ----
    {
        bf16x8 c1hi = *(const bf16x8*)(w1hi + col * 32 + kg * 8);
        bf16x8 c1lo = *(const bf16x8*)(w1lo + col * 32 + kg * 8);
        float c1b = b1[col];
        int ky1 = kg >> 1, kx1 = kg & 1;
        bool wr1 = (kg < 2);
        for (int p = 0; p < 8; ++p) {
            int half = p >> 2, quad = p & 3;
            __syncthreads();   // frL reusable (zeros done / prev conv1 reads done)
            const int* fbase = frame + ((size_t)b0 + (size_t)half * BATCH + quad * 4) * 147;
            #pragma unroll
            for (int i = 0; i < 3; ++i) {
                int idx = i * 256 + t;
                if (idx < 588) {
                    int le = idx / 147, r = idx - le * 147;
                    int cell = r / 3, c = r - cell * 3;
                    int y = cell / 7, x = cell - y * 7;
                    frL[le * 656 + (y + 1) * 72 + (x + 1) * 8 + c] = f2bf((float)fbase[idx]);
                }
            }
            __syncthreads();
            // conv1: 1 elem per wave
            const u16* eb = frL + wv * 656;
            u16* op = p1L + (half * 16 + quad * 4 + wv) * 256;
            #pragma unroll
            for (int mt = 0; mt < 4; ++mt) {
                int posA = mt * 16 + col;
                int oy = posA >> 3, ox = posA & 7;
                bf16x8 a = *(const bf16x8*)(eb + (oy + ky1) * 72 + (ox + kx1) * 8);
                f32x4 acc = {0.f, 0.f, 0.f, 0.f};
                acc = __builtin_amdgcn_mfma_f32_16x16x32_bf16(a, c1hi, acc, 0, 0, 0);
                acc = __builtin_amdgcn_mfma_f32_16x16x32_bf16(a, c1lo, acc, 0, 0, 0);
                float x0 = fmaxf(acc[0] + c1b, 0.f);
                float x1 = fmaxf(acc[1] + c1b, 0.f);
                float x2 = fmaxf(acc[2] + c1b, 0.f);
                float x3 = fmaxf(acc[3] + c1b, 0.f);
                float y0 = fmaxf(x0, x1);
                float y1 = fmaxf(x2, x3);
                float m0 = fmaxf(y0, __shfl_xor(y0, 32, 64));
                float m1 = fmaxf(y1, __shfl_xor(y1, 32, 64));
                if (wr1) {
                    op[(mt * 4 + kg * 2 + 0) * 16 + col] = f2bf(m0);
                    op[(mt * 4 + kg * 2 + 1) * 16 + col] = f2bf(m1);
                }
            }
            // dir/pos scan: full wave, cell = lane (first row-major match = min)
            {
                int best = 49;
                if (l < 49) {
                    int y = l / 7, x = l - y * 7;
                    if (eb[(y + 1) * 72 + (x + 1) * 8] == (u16)0x4120) best = l;  // bf16(10.0)
                }
                best = min(best, __shfl_xor(best, 1, 64));
                best = min(best, __shfl_xor(best, 2, 64));
                best = min(best, __shfl_xor(best, 4, 64));
                best = min(best, __shfl_xor(best, 8, 64));
                best = min(best, __shfl_xor(best, 16, 64));
                best = min(best, __shfl_xor(best, 32, 64));
                if (l == 0) {
                    float dd = 0.f, py = 0.5f, px = 0.5f;
                    if (best < 49) {
                        int y = best / 7, x = best - y * 7;
                        u16 c2 = eb[(y + 1) * 72 + (x + 1) * 8 + 2];
                        dd = (float)(((int)bf2f(c2)) & 3);
                        py = (float)y / 6.0f;
                        px = (float)x / 6.0f;
                    }
                    fdirL[half * 16 + quad * 4 + wv] = make_float4(dd, py, px, 0.f);
                }
            }
        }
    }
    __syncthreads();

    // ---- phase B: conv2+relu+pool (8 elems/wave) ----
    {
        bf16x8 bfrag[2][2];
        #pragma unroll
        for (int s = 0; s < 2; ++s)
            #pragma unroll
            for (int nt = 0; nt < 2; ++nt)
                bfrag[s][nt] = *(const bf16x8*)(w2r + (nt * 16 + col) * 64 + s * 32 + kg * 8);
        float bias2[2] = { b2[col], b2[16 + col] };
        int oy = col >> 2, ox = col & 3;
        int aoff[2]; bool aok[2];
        #pragma unroll
        for (int s = 0; s < 2; ++s) {
            int tap = 2 * s + (kg >> 1);
            int ky = tap >> 1, kx = tap & 1;
            int iy = oy - 1 + ky, ix = ox - 1 + kx;
            aok[s] = (iy >= 0 && ix >= 0);
            aoff[s] = (iy * 4 + ix) * 16 + (kg & 1) * 8;
        }
        #pragma unroll
        for (int q = 0; q < 8; ++q) {
            int e = wv * 8 + q;
            const u16* pbase = p1L + e * 256;
            bf16x8 a0 = {0,0,0,0,0,0,0,0}, a1 = {0,0,0,0,0,0,0,0};
            if (aok[0]) a0 = *(const bf16x8*)(pbase + aoff[0]);
            if (aok[1]) a1 = *(const bf16x8*)(pbase + aoff[1]);
            f32x4 acc0 = {0.f,0.f,0.f,0.f}, acc1 = {0.f,0.f,0.f,0.f};
            acc0 = __builtin_amdgcn_mfma_f32_16x16x32_bf16(a0, bfrag[0][0], acc0, 0, 0, 0);
            acc1 = __builtin_amdgcn_mfma_f32_16x16x32_bf16(a0, bfrag[0][1], acc1, 0, 0, 0);
            acc0 = __builtin_amdgcn_mfma_f32_16x16x32_bf16(a1, bfrag[1][0], acc0, 0, 0, 0);
            acc1 = __builtin_amdgcn_mfma_f32_16x16x32_bf16(a1, bfrag[1][1], acc1, 0, 0, 0);
            #pragma unroll
            for (int nt = 0; nt < 2; ++nt) {
                f32x4 acc = nt ? acc1 : acc0;
                float b = bias2[nt];
                float m0 = fmaxf(fmaxf(acc[0] + b, 0.f), fmaxf(acc[1] + b, 0.f));
                float m1 = fmaxf(fmaxf(acc[2] + b, 0.f), fmaxf(acc[3] + b, 0.f));
                float p0 = fmaxf(m0, __shfl_xor(m0, 16, 64));
                float p1 = fmaxf(m1, __shfl_xor(m1, 16, 64));
                if ((kg & 1) == 0) {
                    int qq = (kg >> 1) * 2;
                    u16* op = p2L + e * 128 + nt * 16 + col;
                    op[qq * 32]       = f2bf(p0);
                    op[(qq + 1) * 32] = f2bf(p1);
                }
            }
        }
    }

    int colhi = col >> 3, collo = col & 7;
    // ---- phases C+D per 16-elem half: conv3 -> featL -> proj -> combL --
    for (int half = 0; half < 2; ++half) {
        __syncthreads();   // featL writable (p1L dead / prev D reads done)
        {
            bf16x8 bfrag[4][4];
            #pragma unroll
            for (int s = 0; s < 4; ++s)
                #pragma unroll
                for (int nt = 0; nt < 4; ++nt)
                    bfrag[s][nt] = *(const bf16x8*)(w3r + (nt * 16 + col) * 128 + s * 32 + kg * 8);
            float bias[4];
            #pragma unroll
            for (int nt = 0; nt < 4; ++nt) bias[nt] = b3[nt * 16 + col];

            auto do_tile = [&](int i) {
                int m0 = i * 16;
                int m = m0 + col;
                u32 elem = (u32)(((unsigned long long)(u32)m * 954437177ull) >> 33); // m/9
                int p = m - (int)elem * 9;
                int oy = (p * 86) >> 8;
                int ox = p - 3 * oy;
                const u16* pbase = p2L + (half * 16 + (int)elem) * 128 + kg * 8;
                f32x4 acc[4];
                #pragma unroll
                for (int nt = 0; nt < 4; ++nt) {
                    acc[nt][0] = 0.f; acc[nt][1] = 0.f; acc[nt][2] = 0.f; acc[nt][3] = 0.f;
                }
                #pragma unroll
                for (int s = 0; s < 4; ++s) {
                    int ky = s >> 1, kx = s & 1;
                    int iy = oy - 1 + ky, ix = ox - 1 + kx;
                    bf16x8 a = {0,0,0,0,0,0,0,0};
                    if (iy >= 0 && iy <= 1 && ix >= 0 && ix <= 1)
                        a = *(const bf16x8*)(pbase + (iy * 2 + ix) * 32);
                    #pragma unroll
                    for (int nt = 0; nt < 4; ++nt)
                        acc[nt] = __builtin_amdgcn_mfma_f32_16x16x32_bf16(a, bfrag[s][nt], acc[nt], 0, 0, 0);
                }
                #pragma unroll
                for (int r = 0; r < 4; ++r) {
                    int mr = m0 + kg * 4 + r;
                    u32 er = (u32)(((unsigned long long)(u32)mr * 954437177ull) >> 33);
                    int pr = mr - (int)er * 9;
                    int e7 = (int)(er & 7u);
                    u16* fb = featL + er * 640 + collo;
                    #pragma unroll
                    for (int nt = 0; nt < 4; ++nt) {
                        int blk = (pr * 8 + nt * 2 + colhi) ^ e7;
                        fb[blk * 8] = f2bf(fmaxf(acc[nt][r] + bias[nt], 0.f));
                    }
                }
            };
            do_tile(wv);
            do_tile(wv + 4);
            if (wv == 0) do_tile(8);
        }
        if (t < 16) {
            int g = b0 + half * BATCH + t;
            union { u16 s[8]; uint4 q; } b;
            b.s[0] = f2bf((float)ccol[g]);
            b.s[1] = f2bf((float)cobj[g]);
            #pragma unroll
            for (int i = 2; i < 8; ++i) b.s[i] = 0;
            *(uint4*)(featL + t * 640 + (72 ^ (t & 7)) * 8) = b.q;
        }
        __syncthreads();

        // ---- phase D: proj (16 rows); wave = n-quarter ----
        {
            const u16* arowb = featL + col * 640;
            int rx = col & 7;
            const u16* brow = pwT + (wv * 16 + col) * 608 + kg * 8;
            f32x4 acc = {0.f, 0.f, 0.f, 0.f};
            #pragma unroll
            for (int k0 = 0; k0 < 608; k0 += 32) {
                bf16x8 a;
                if (k0 + kg * 8 < 584) {
                    int L = (k0 >> 3) + kg;
                    a = *(const bf16x8*)(arowb + (L ^ rx) * 8);
                } else {
                    #pragma unroll
                    for (int j = 0; j < 8; ++j) a[j] = 0;
                }
                bf16x8 bf = *(const bf16x8*)(brow + k0);
                acc = __builtin_amdgcn_mfma_f32_16x16x32_bf16(a, bf, acc, 0, 0, 0);
            }
            int n = wv * 16 + col;
            float pbv = pb[n];
            #pragma unroll
            for (int r = 0; r < 4; ++r) {
                combL[(kg * 4 + r) * 128 + half * 64 + n] = fmaxf(acc[r] + pbv, 0.f);
            }
        }
    }
    __syncthreads();

    // ---- phase E: h1 GEMM (M=16); waves split N (2 n-tiles each) ----
    {
        const float* arow = combL + col * 128 + kg * 8;
        f32x4 acc[2];
        acc[0][0]=0.f; acc[0][1]=0.f; acc[0][2]=0.f; acc[0][3]=0.f;
        acc[1][0]=0.f; acc[1][1]=0.f; acc[1][2]=0.f; acc[1][3]=0.f;
        #pragma unroll
        for (int s = 0; s < 5; ++s) {
            float x[8];
            if (s < 4) {
                #pragma unroll
                for (int j = 0; j < 8; ++j) x[j] = arow[s * 32 + j];
            } else {
                #pragma unroll
                for (int j = 0; j < 8; ++j) x[j] = 0.f;
                if (kg == 0) {
                    float4 f0 = fdirL[col];
                    float4 f1 = fdirL[16 + col];
                    int delta = (((int)f1.x) - ((int)f0.x) + 4) & 3;
                    const float ANG = (float)(2.0 * 3.14159 / 4.0);
                    float angle = (float)delta * ANG;
                    x[0] = sinf(angle);
                    x[1] = cosf(angle);
                    x[2] = f1.y - f0.y;
                    x[3] = f1.z - f0.z;
                }
            }
            bf16x8 ahi, alo;
            split8(x, ahi, alo);
            #pragma unroll
            for (int nt = 0; nt < 2; ++nt) {
                int n0 = (wv * 2 + nt) * 16 + col;
                bf16x8 bhiF = *(const bf16x8*)(h1hi + n0 * 160 + s * 32 + kg * 8);
                bf16x8 bloF = *(const bf16x8*)(h1lo + n0 * 160 + s * 32 + kg * 8);
                acc[nt] = __builtin_amdgcn_mfma_f32_16x16x32_bf16(ahi, bhiF, acc[nt], 0, 0, 0);
                acc[nt] = __builtin_amdgcn_mfma_f32_16x16x32_bf16(alo, bhiF, acc[nt], 0, 0, 0);
                acc[nt] = __builtin_amdgcn_mfma_f32_16x16x32_bf16(ahi, bloF, acc[nt], 0, 0, 0);
            }
        }
        __syncthreads();   // combL reads done before hL (separate region, but cheap)
        #pragma unroll
        for (int nt = 0; nt < 2; ++nt) {
            int n = (wv * 2 + nt) * 16 + col;
            float bv = h1b[n];
            #pragma unroll
            for (int r = 0; r < 4; ++r)
                hL[(kg * 4 + r) * 132 + n] = acc[nt][r] + bv;
        }
    }
    __syncthreads();

    // ---- phase F: LN + relu in place (4 rows/wave) ----
    #pragma unroll
    for (int rr = 0; rr < 4; ++rr) {
        float* rp = hL + (wv * 4 + rr) * 132 + l * 2;
        float2 v = *(const float2*)rp;
        float s = v.x + v.y;
        s += __shfl_xor(s, 1, 64);
        s += __shfl_xor(s, 2, 64);
        s += __shfl_xor(s, 4, 64);
        s += __shfl_xor(s, 8, 64);
        s += __shfl_xor(s, 16, 64);
        s += __shfl_xor(s, 32, 64);
        float mu = s * (1.0f / 128.0f);
        float d0 = v.x - mu, d1 = v.y - mu;
        float vs = d0 * d0 + d1 * d1;
        vs += __shfl_xor(vs, 1, 64);
        vs += __shfl_xor(vs, 2, 64);
        vs += __shfl_xor(vs, 4, 64);
        vs += __shfl_xor(vs, 8, 64);
        vs += __shfl_xor(vs, 16, 64);
        vs += __shfl_xor(vs, 32, 64);
        float rs = rsqrtf(vs * (1.0f / 128.0f) + 1e-5f);
        float2 o;
        o.x = fmaxf(d0 * rs * lng[l * 2]     + lnb[l * 2],     0.f);
        o.y = fmaxf(d1 * rs * lng[l * 2 + 1] + lnb[l * 2 + 1], 0.f);
        *(float2*)rp = o;
    }
    __syncthreads();

    // ---- phase G: h2 GEMM (M=16); waves split N; barrier pre-epilogue --
    {
        const float* arow = hL + col * 132 + kg * 8;
        f32x4 acc[2];
        acc[0][0]=0.f; acc[0][1]=0.f; acc[0][2]=0.f; acc[0][3]=0.f;
        acc[1][0]=0.f; acc[1][1]=0.f; acc[1][2]=0.f; acc[1][3]=0.f;
        #pragma unroll
        for (int s = 0; s < 4; ++s) {
            float x[8];
            #pragma unroll
            for (int j = 0; j < 8; ++j) x[j] = arow[s * 32 + j];
            bf16x8 ahi, alo;
            split8(x, ahi, alo);
            #pragma unroll
            for (int nt = 0; nt < 2; ++nt) {
                int n0 = (wv * 2 + nt) * 16 + col;
                bf16x8 bhiF = *(const bf16x8*)(h2hi + n0 * 128 + s * 32 + kg * 8);
                bf16x8 bloF = *(const bf16x8*)(h2lo + n0 * 128 + s * 32 + kg * 8);
                acc[nt] = __builtin_amdgcn_mfma_f32_16x16x32_bf16(ahi, bhiF, acc[nt], 0, 0, 0);
                acc[nt] = __builtin_amdgcn_mfma_f32_16x16x32_bf16(alo, bhiF, acc[nt], 0, 0, 0);
                acc[nt] = __builtin_amdgcn_mfma_f32_16x16x32_bf16(ahi, bloF, acc[nt], 0, 0, 0);
            }
        }
        __syncthreads();   // all A reads done before in-place writes
        #pragma unroll
        for (int nt = 0; nt < 2; ++nt) {
            int n = (wv * 2 + nt) * 16 + col;
            float bv = h2b[n];
            #pragma unroll
            for (int r = 0; r < 4; ++r)
                hL[(kg * 4 + r) * 132 + n] = fmaxf(acc[nt][r] + bv, 0.f);
        }
    }
    __syncthreads();

    // ---- phase H: h3; t<112: (row, j) ----
    if (t < 112) {
        int row = t / 7, j = t - row * 7;
        const float* rp = hL + row * 132;
        float a0 = h3b[j];
        const float* wr0 = h3w + j * 128;
        #pragma unroll 4
        for (int c = 0; c < 32; ++c) {
            float4 v = *(const float4*)(rp + c * 4);
            a0 += v.x * wr0[c * 4 + 0];
            a0 += v.y * wr0[c * 4 + 1];
            a0 += v.z * wr0[c * 4 + 2];
            a0 += v.w * wr0[c * 4 + 3];
        }
        out[(size_t)(b0 + row) * 7 + j] = a0;
    }
}

extern "C" void kernel_launch(void* const* d_in, const int* in_sizes, int n_in,
                              void* d_out, int out_size, void* d_ws, size_t ws_size,
                              hipStream_t stream) {
    const int*   frame = (const int*)d_in[0];
    const int*   ccol  = (const int*)d_in[1];
    const int*   cobj  = (const int*)d_in[2];
    const float* w1    = (const float*)d_in[3];
    const float* b1    = (const float*)d_in[4];
    const float* w2    = (const float*)d_in[5];
    const float* b2    = (const float*)d_in[6];
    const float* w3    = (const float*)d_in[7];
    const float* b3    = (const float*)d_in[8];
    const float* pw    = (const float*)d_in[9];
    const float* pb    = (const float*)d_in[10];
    const float* h1w   = (const float*)d_in[11];
    const float* h1b   = (const float*)d_in[12];
    const float* lng   = (const float*)d_in[13];
    const float* lnb   = (const float*)d_in[14];
    const float* h2w   = (const float*)d_in[15];
    const float* h2b   = (const float*)d_in[16];
    const float* h3w   = (const float*)d_in[17];
    const float* h3b   = (const float*)d_in[18];
    float* out = (float*)d_out;

    char* ws = (char*)d_ws;
    u16*   pwT      = (u16*)(ws + 0);                    // 77824 B
    u16*   w2r      = (u16*)(ws + 131072);               // 4096 B
    u16*   w3r      = (u16*)(ws + 139264);               // 16384 B
    u16*   h2hi     = (u16*)(ws + 163840);               // 32768 B
    u16*   h2lo     = (u16*)(ws + 196608);               // 32768 B
    u16*   h1hi     = (u16*)(ws + 229376);               // 40960 B
    u16*   h1lo     = (u16*)(ws + 270336);               // 40960 B
    u16*   w1hi     = (u16*)(ws + 311296);               // 1024 B
    u16*   w1lo     = (u16*)(ws + 312320);               // 1024 B

    k0_prep<<<340, 256, 0, stream>>>(pw, w2, w3, h2w, h1w, w1,
                                     pwT, w2r, w3r, h2hi, h2lo, h1hi, h1lo,
                                     w1hi, w1lo);
    kall<<<2048, 256, 0, stream>>>(frame, w1hi, w1lo, b1, w2r, b2,
                                   w3r, b3, ccol, cobj, pwT, pb,
                                   h1hi, h1lo, h1b, lng, lnb,
                                   h2hi, h2lo, h2b, h3w, h3b, out);
}

// Round 24
// 218.807 us; speedup vs baseline: 1.2345x; 1.2345x over previous
//
#include <hip/hip_runtime.h>
#include <hip/hip_bf16.h>

#define BATCH 32768
#define NELEM 65536   // 2 * BATCH

typedef unsigned short u16;
typedef unsigned int u32;
typedef __attribute__((ext_vector_type(8))) short bf16x8;
typedef __attribute__((ext_vector_type(4))) float f32x4;

__device__ __forceinline__ float bf2f(u16 u) {
    union { u32 u; float f; } c; c.u = ((u32)u) << 16; return c.f;
}
__device__ __forceinline__ u16 f2bf(float f) {
    union { float f; u32 u; } c; c.f = f;
    u32 x = c.u;
    u32 r = (x + 0x7fffu + ((x >> 16) & 1u)) >> 16;  // RNE
    return (u16)r;
}

// ---------------- K0: weight prep ---------------------------------------
__global__ __launch_bounds__(256) void k0_prep(const float* __restrict__ pw,
        const float* __restrict__ w2, const float* __restrict__ w3,
        const float* __restrict__ h2w, const float* __restrict__ h1w,
        const float* __restrict__ w1,
        u16* __restrict__ pwT, u16* __restrict__ w2r, u16* __restrict__ w3r,
        u16* __restrict__ h2hi, u16* __restrict__ h2lo,
        u16* __restrict__ h1hi, u16* __restrict__ h1lo,
        u16* __restrict__ w1hi, u16* __restrict__ w1lo) {
    int idx = blockIdx.x * 256 + threadIdx.x;
    if (idx < 38912) {
        int j = idx / 608, kk = idx - j * 608;
        float v = 0.f;
        if (kk < 576) {
            int p = kk >> 6, oc = kk & 63;
            v = pw[j * 578 + oc * 9 + p];
        } else if (kk < 578) {
            v = pw[j * 578 + kk];
        }
        pwT[idx] = f2bf(v);
    } else if (idx < 40960) {
        int i = idx - 38912;
        int oc = i >> 6, rem = i & 63, tap = rem >> 4, ic = rem & 15;
        w2r[i] = f2bf(w2[oc * 64 + ic * 4 + tap]);
    } else if (idx < 49152) {
        int i = idx - 40960;
        int oc = i >> 7, rem = i & 127, tap = rem >> 5, ic = rem & 31;
        w3r[i] = f2bf(w3[oc * 128 + ic * 4 + tap]);
    } else if (idx < 65536) {
        int i = idx - 49152;
        float v = h2w[i];
        u16 hi = f2bf(v);
        h2hi[i] = hi;
        h2lo[i] = f2bf(v - bf2f(hi));
    } else if (idx < 86016) {
        int i = idx - 65536;
        int j = i / 160, k = i - j * 160;
        float v = (k < 132) ? h1w[j * 132 + k] : 0.f;
        u16 hi = f2bf(v);
        h1hi[i] = hi;
        h1lo[i] = f2bf(v - bf2f(hi));
    } else if (idx < 86528) {
        int i = idx - 86016;               // [oc16][k32]
        int oc = i >> 5, k = i & 31;
        int ky = k >> 4, kx = (k >> 3) & 1, c = k & 7;
        float v = (c < 3) ? w1[oc * 12 + c * 4 + ky * 2 + kx] : 0.f;
        u16 hi = f2bf(v);
        w1hi[i] = hi;
        w1lo[i] = f2bf(v - bf2f(hi));
    }
}

__device__ __forceinline__ void split8(const float* __restrict__ x,
                                       bf16x8& hi, bf16x8& lo) {
    #pragma unroll
    for (int j = 0; j < 8; ++j) {
        u16 h = f2bf(x[j]);
        hi[j] = (short)h;
        lo[j] = (short)f2bf(x[j] - bf2f(h));
    }
}

// ---------------- KALL: whole network, one block = 16 batch rows --------
// R21-validated configuration (best: 219.7 us total). Elems: local 0..15 =
// curr (b0+i), 16..31 = next (b0+BATCH+i). Conv phases A-D; proj writes
// combL in LDS; MLP phases E-H finish the 16 rows. LDS overlays: combL
// over dead p2L; hL over dead featL. 49664 B -> 3 blocks/CU, VGPR 68.
__global__ __launch_bounds__(256) void kall(const int* __restrict__ frame,
        const u16* __restrict__ w1hi, const u16* __restrict__ w1lo,
        const float* __restrict__ b1,
        const u16* __restrict__ w2r, const float* __restrict__ b2,
        const u16* __restrict__ w3r, const float* __restrict__ b3,
        const int* __restrict__ ccol, const int* __restrict__ cobj,
        const u16* __restrict__ pwT, const float* __restrict__ pb,
        const u16* __restrict__ h1hi, const u16* __restrict__ h1lo,
        const float* __restrict__ h1b,
        const float* __restrict__ lng, const float* __restrict__ lnb,
        const u16* __restrict__ h2hi, const u16* __restrict__ h2lo,
        const float* __restrict__ h2b,
        const float* __restrict__ h3w, const float* __restrict__ h3b,
        float* __restrict__ out) {
    __shared__ u16 lds[24576];     // 49152 B
    __shared__ float4 fdirL[32];   // 512 B
    u16* p2L   = lds;              // [0,4096)
    u16* p1L   = lds + 4096;       // [4096,12288)
    u16* frL   = lds + 12288;      // 16*656 ends 22784
    u16* featL = lds + 4096;       // [4096,24576) overlay
    float* combL = (float*)lds;            // 16*128 floats = 4096 u16 (over p2L)
    float* hL    = (float*)(lds + 4096);   // 16*132 floats = 8448 u16 (over featL)
    int t = threadIdx.x;
    int l = t & 63;
    int wv = t >> 6;
    int col = l & 15;
    int kg = l >> 4;
    int b0 = blockIdx.x * 16;

    #pragma unroll
    for (int i = 0; i < 6; ++i) {
        int o = i * 256 + t;
        if (o < 1312) *(uint4*)(frL + o * 8) = make_uint4(0u, 0u, 0u, 0u);
    }

    // ---- phase A: conv1+relu+pool (h=0 curr, h=1 next) + dir scan ----
    {
        bf16x8 c1hi = *(const bf16x8*)(w1hi + col * 32 + kg * 8);
        bf16x8 c1lo = *(const bf16x8*)(w1lo + col * 32 + kg * 8);
        float c1b = b1[col];
        int ky1 = kg >> 1, kx1 = kg & 1;
        bool wr1 = (kg < 2);
        for (int h = 0; h < 2; ++h) {
            __syncthreads();
            const int* fbase = frame + ((size_t)b0 + (size_t)h * BATCH) * 147;
            #pragma unroll
            for (int i = 0; i < 10; ++i) {
                int idx = i * 256 + t;
                if (idx < 2352) {
                    int le = idx / 147, r = idx - le * 147;
                    int cell = r / 3, c = r - cell * 3;
                    int y = cell / 7, x = cell - y * 7;
                    frL[le * 656 + (y + 1) * 72 + (x + 1) * 8 + c] = f2bf((float)fbase[idx]);
                }
            }
            __syncthreads();
            #pragma unroll
            for (int q = 0; q < 4; ++q) {
                int le = wv * 4 + q;
                const u16* eb = frL + le * 656;
                u16* op = p1L + (h * 16 + le) * 256;
                #pragma unroll
                for (int mt = 0; mt < 4; ++mt) {
                    int posA = mt * 16 + col;
                    int oy = posA >> 3, ox = posA & 7;
                    bf16x8 a = *(const bf16x8*)(eb + (oy + ky1) * 72 + (ox + kx1) * 8);
                    f32x4 acc = {0.f, 0.f, 0.f, 0.f};
                    acc = __builtin_amdgcn_mfma_f32_16x16x32_bf16(a, c1hi, acc, 0, 0, 0);
                    acc = __builtin_amdgcn_mfma_f32_16x16x32_bf16(a, c1lo, acc, 0, 0, 0);
                    float x0 = fmaxf(acc[0] + c1b, 0.f);
                    float x1 = fmaxf(acc[1] + c1b, 0.f);
                    float x2 = fmaxf(acc[2] + c1b, 0.f);
                    float x3 = fmaxf(acc[3] + c1b, 0.f);
                    float y0 = fmaxf(x0, x1);
                    float y1 = fmaxf(x2, x3);
                    float m0 = fmaxf(y0, __shfl_xor(y0, 32, 64));
                    float m1 = fmaxf(y1, __shfl_xor(y1, 32, 64));
                    if (wr1) {
                        op[(mt * 4 + kg * 2 + 0) * 16 + col] = f2bf(m0);
                        op[(mt * 4 + kg * 2 + 1) * 16 + col] = f2bf(m1);
                    }
                }
            }
            // ---- dir/pos scan (16-lane group per elem) ----
            {
                int le = wv * 4 + kg;
                const u16* eb = frL + le * 656;
                int best = 49;
                #pragma unroll
                for (int q2 = 0; q2 < 4; ++q2) {
                    int cell = col + q2 * 16;
                    if (cell < 49) {
                        int y = cell / 7, x = cell - y * 7;
                        u16 v = eb[(y + 1) * 72 + (x + 1) * 8];
                        if (v == (u16)0x4120 && cell < best) best = cell;  // bf16(10.0)
                    }
                }
                best = min(best, __shfl_xor(best, 1, 64));
                best = min(best, __shfl_xor(best, 2, 64));
                best = min(best, __shfl_xor(best, 4, 64));
                best = min(best, __shfl_xor(best, 8, 64));
                if (col == 0) {
                    float dd = 0.f, py = 0.5f, px = 0.5f;
                    if (best < 49) {
                        int y = best / 7, x = best - y * 7;
                        u16 c2 = eb[(y + 1) * 72 + (x + 1) * 8 + 2];
                        dd = (float)(((int)bf2f(c2)) & 3);
                        py = (float)y / 6.0f;
                        px = (float)x / 6.0f;
                    }
                    fdirL[h * 16 + le] = make_float4(dd, py, px, 0.f);
                }
            }
        }
    }
    __syncthreads();

    // ---- phase B: conv2+relu+pool (8 elems/wave) ----
    {
        bf16x8 bfrag[2][2];
        #pragma unroll
        for (int s = 0; s < 2; ++s)
            #pragma unroll
            for (int nt = 0; nt < 2; ++nt)
                bfrag[s][nt] = *(const bf16x8*)(w2r + (nt * 16 + col) * 64 + s * 32 + kg * 8);
        float bias2[2] = { b2[col], b2[16 + col] };
        int oy = col >> 2, ox = col & 3;
        int aoff[2]; bool aok[2];
        #pragma unroll
        for (int s = 0; s < 2; ++s) {
            int tap = 2 * s + (kg >> 1);
            int ky = tap >> 1, kx = tap & 1;
            int iy = oy - 1 + ky, ix = ox - 1 + kx;
            aok[s] = (iy >= 0 && ix >= 0);
            aoff[s] = (iy * 4 + ix) * 16 + (kg & 1) * 8;
        }
        #pragma unroll
        for (int q = 0; q < 8; ++q) {
            int e = wv * 8 + q;
            const u16* pbase = p1L + e * 256;
            bf16x8 a0 = {0,0,0,0,0,0,0,0}, a1 = {0,0,0,0,0,0,0,0};
            if (aok[0]) a0 = *(const bf16x8*)(pbase + aoff[0]);
            if (aok[1]) a1 = *(const bf16x8*)(pbase + aoff[1]);
            f32x4 acc0 = {0.f,0.f,0.f,0.f}, acc1 = {0.f,0.f,0.f,0.f};
            acc0 = __builtin_amdgcn_mfma_f32_16x16x32_bf16(a0, bfrag[0][0], acc0, 0, 0, 0);
            acc1 = __builtin_amdgcn_mfma_f32_16x16x32_bf16(a0, bfrag[0][1], acc1, 0, 0, 0);
            acc0 = __builtin_amdgcn_mfma_f32_16x16x32_bf16(a1, bfrag[1][0], acc0, 0, 0, 0);
            acc1 = __builtin_amdgcn_mfma_f32_16x16x32_bf16(a1, bfrag[1][1], acc1, 0, 0, 0);
            #pragma unroll
            for (int nt = 0; nt < 2; ++nt) {
                f32x4 acc = nt ? acc1 : acc0;
                float b = bias2[nt];
                float m0 = fmaxf(fmaxf(acc[0] + b, 0.f), fmaxf(acc[1] + b, 0.f));
                float m1 = fmaxf(fmaxf(acc[2] + b, 0.f), fmaxf(acc[3] + b, 0.f));
                float p0 = fmaxf(m0, __shfl_xor(m0, 16, 64));
                float p1 = fmaxf(m1, __shfl_xor(m1, 16, 64));
                if ((kg & 1) == 0) {
                    int qq = (kg >> 1) * 2;
                    u16* op = p2L + e * 128 + nt * 16 + col;
                    op[qq * 32]       = f2bf(p0);
                    op[(qq + 1) * 32] = f2bf(p1);
                }
            }
        }
    }
    __syncthreads();   // p1L dead; featL writable

    int colhi = col >> 3, collo = col & 7;
    // ---- phase C: conv3 (18 tiles; 4/wave + extra for wv<2) ----
    {
        bf16x8 bfrag[4][4];
        #pragma unroll
        for (int s = 0; s < 4; ++s)
            #pragma unroll
            for (int nt = 0; nt < 4; ++nt)
                bfrag[s][nt] = *(const bf16x8*)(w3r + (nt * 16 + col) * 128 + s * 32 + kg * 8);
        float bias[4];
        #pragma unroll
        for (int nt = 0; nt < 4; ++nt) bias[nt] = b3[nt * 16 + col];

        auto do_tile = [&](int i) {
            int m0 = i * 16;
            int m = m0 + col;
            u32 elem = (u32)(((unsigned long long)(u32)m * 954437177ull) >> 33); // m/9
            int p = m - (int)elem * 9;
            int oy = (p * 86) >> 8;
            int ox = p - 3 * oy;
            const u16* pbase = p2L + elem * 128 + kg * 8;
            f32x4 acc[4];
            #pragma unroll
            for (int nt = 0; nt < 4; ++nt) {
                acc[nt][0] = 0.f; acc[nt][1] = 0.f; acc[nt][2] = 0.f; acc[nt][3] = 0.f;
            }
            #pragma unroll
            for (int s = 0; s < 4; ++s) {
                int ky = s >> 1, kx = s & 1;
                int iy = oy - 1 + ky, ix = ox - 1 + kx;
                bf16x8 a = {0,0,0,0,0,0,0,0};
                if (iy >= 0 && iy <= 1 && ix >= 0 && ix <= 1)
                    a = *(const bf16x8*)(pbase + (iy * 2 + ix) * 32);
                #pragma unroll
                for (int nt = 0; nt < 4; ++nt)
                    acc[nt] = __builtin_amdgcn_mfma_f32_16x16x32_bf16(a, bfrag[s][nt], acc[nt], 0, 0, 0);
            }
            #pragma unroll
            for (int r = 0; r < 4; ++r) {
                int mr = m0 + kg * 4 + r;
                u32 er = (u32)(((unsigned long long)(u32)mr * 954437177ull) >> 33);
                int pr = mr - (int)er * 9;
                int e7 = (int)(er & 7u);
                u16* fb = featL + er * 640 + collo;
                #pragma unroll
                for (int nt = 0; nt < 4; ++nt) {
                    int blk = (pr * 8 + nt * 2 + colhi) ^ e7;
                    fb[blk * 8] = f2bf(fmaxf(acc[nt][r] + bias[nt], 0.f));
                }
            }
        };
        #pragma unroll
        for (int u = 0; u < 4; ++u) do_tile(wv + u * 4);
        if (wv < 2) do_tile(16 + wv);
    }
    if (t < 32) {
        int g = b0 + (t >> 4) * BATCH + (t & 15);
        union { u16 s[8]; uint4 q; } b;
        b.s[0] = f2bf((float)ccol[g]);
        b.s[1] = f2bf((float)cobj[g]);
        #pragma unroll
        for (int i = 2; i < 8; ++i) b.s[i] = 0;
        *(uint4*)(featL + t * 640 + (72 ^ (t & 7)) * 8) = b.q;
    }
    __syncthreads();

    // ---- phase D: proj -> combL; wave = (row-half rh, n-half nh) ----
    {
        int rh = wv & 1, nh = wv >> 1;
        const u16* arowb = featL + (rh * 16 + col) * 640;
        int rx = col & 7;
        const u16* brow = pwT + (nh * 32 + col) * 608 + kg * 8;
        f32x4 acc0 = {0.f,0.f,0.f,0.f}, acc1 = {0.f,0.f,0.f,0.f};
        #pragma unroll
        for (int k0 = 0; k0 < 608; k0 += 32) {
            bf16x8 a;
            if (k0 + kg * 8 < 584) {
                int L = (k0 >> 3) + kg;
                a = *(const bf16x8*)(arowb + (L ^ rx) * 8);
            } else {
                #pragma unroll
                for (int j = 0; j < 8; ++j) a[j] = 0;
            }
            bf16x8 b0f = *(const bf16x8*)(brow + k0);
            bf16x8 b1f = *(const bf16x8*)(brow + 16 * 608 + k0);
            acc0 = __builtin_amdgcn_mfma_f32_16x16x32_bf16(a, b0f, acc0, 0, 0, 0);
            acc1 = __builtin_amdgcn_mfma_f32_16x16x32_bf16(a, b1f, acc1, 0, 0, 0);
        }
        __syncthreads();   // featL reads done everywhere before combL/hL writes
        #pragma unroll
        for (int nt = 0; nt < 2; ++nt) {
            int n = nh * 32 + nt * 16 + col;
            float pbv = pb[n];
            f32x4 acc = nt ? acc1 : acc0;
            #pragma unroll
            for (int r = 0; r < 4; ++r) {
                // local elem = rh*16 + kg*4 + r -> batch row kg*4+r, half rh
                combL[(kg * 4 + r) * 128 + rh * 64 + n] = fmaxf(acc[r] + pbv, 0.f);
            }
        }
    }
    __syncthreads();

    // ---- phase E: h1 GEMM (M=16); waves split N (2 n-tiles each) ----
    {
        const float* arow = combL + col * 128 + kg * 8;
        f32x4 acc[2];
        acc[0][0]=0.f; acc[0][1]=0.f; acc[0][2]=0.f; acc[0][3]=0.f;
        acc[1][0]=0.f; acc[1][1]=0.f; acc[1][2]=0.f; acc[1][3]=0.f;
        #pragma unroll
        for (int s = 0; s < 5; ++s) {
            float x[8];
            if (s < 4) {
                #pragma unroll
                for (int j = 0; j < 8; ++j) x[j] = arow[s * 32 + j];
            } else {
                #pragma unroll
                for (int j = 0; j < 8; ++j) x[j] = 0.f;
                if (kg == 0) {
                    float4 f0 = fdirL[col];
                    float4 f1 = fdirL[16 + col];
                    int delta = (((int)f1.x) - ((int)f0.x) + 4) & 3;
                    const float ANG = (float)(2.0 * 3.14159 / 4.0);
                    float angle = (float)delta * ANG;
                    x[0] = sinf(angle);
                    x[1] = cosf(angle);
                    x[2] = f1.y - f0.y;
                    x[3] = f1.z - f0.z;
                }
            }
            bf16x8 ahi, alo;
            split8(x, ahi, alo);
            #pragma unroll
            for (int nt = 0; nt < 2; ++nt) {
                int n0 = (wv * 2 + nt) * 16 + col;
                bf16x8 bhiF = *(const bf16x8*)(h1hi + n0 * 160 + s * 32 + kg * 8);
                bf16x8 bloF = *(const bf16x8*)(h1lo + n0 * 160 + s * 32 + kg * 8);
                acc[nt] = __builtin_amdgcn_mfma_f32_16x16x32_bf16(ahi, bhiF, acc[nt], 0, 0, 0);
                acc[nt] = __builtin_amdgcn_mfma_f32_16x16x32_bf16(alo, bhiF, acc[nt], 0, 0, 0);
                acc[nt] = __builtin_amdgcn_mfma_f32_16x16x32_bf16(ahi, bloF, acc[nt], 0, 0, 0);
            }
        }
        #pragma unroll
        for (int nt = 0; nt < 2; ++nt) {
            int n = (wv * 2 + nt) * 16 + col;
            float bv = h1b[n];
            #pragma unroll
            for (int r = 0; r < 4; ++r)
                hL[(kg * 4 + r) * 132 + n] = acc[nt][r] + bv;
        }
    }
    __syncthreads();

    // ---- phase F: LN + relu in place (4 rows/wave) ----
    #pragma unroll
    for (int rr = 0; rr < 4; ++rr) {
        float* rp = hL + (wv * 4 + rr) * 132 + l * 2;
        float2 v = *(const float2*)rp;
        float s = v.x + v.y;
        s += __shfl_xor(s, 1, 64);
        s += __shfl_xor(s, 2, 64);
        s += __shfl_xor(s, 4, 64);
        s += __shfl_xor(s, 8, 64);
        s += __shfl_xor(s, 16, 64);
        s += __shfl_xor(s, 32, 64);
        float mu = s * (1.0f / 128.0f);
        float d0 = v.x - mu, d1 = v.y - mu;
        float vs = d0 * d0 + d1 * d1;
        vs += __shfl_xor(vs, 1, 64);
        vs += __shfl_xor(vs, 2, 64);
        vs += __shfl_xor(vs, 4, 64);
        vs += __shfl_xor(vs, 8, 64);
        vs += __shfl_xor(vs, 16, 64);
        vs += __shfl_xor(vs, 32, 64);
        float rs = rsqrtf(vs * (1.0f / 128.0f) + 1e-5f);
        float2 o;
        o.x = fmaxf(d0 * rs * lng[l * 2]     + lnb[l * 2],     0.f);
        o.y = fmaxf(d1 * rs * lng[l * 2 + 1] + lnb[l * 2 + 1], 0.f);
        *(float2*)rp = o;
    }
    __syncthreads();

    // ---- phase G: h2 GEMM (M=16); waves split N; barrier pre-epilogue --
    {
        const float* arow = hL + col * 132 + kg * 8;
        f32x4 acc[2];
        acc[0][0]=0.f; acc[0][1]=0.f; acc[0][2]=0.f; acc[0][3]=0.f;
        acc[1][0]=0.f; acc[1][1]=0.f; acc[1][2]=0.f; acc[1][3]=0.f;
        #pragma unroll
        for (int s = 0; s < 4; ++s) {
            float x[8];
            #pragma unroll
            for (int j = 0; j < 8; ++j) x[j] = arow[s * 32 + j];
            bf16x8 ahi, alo;
            split8(x, ahi, alo);
            #pragma unroll
            for (int nt = 0; nt < 2; ++nt) {
                int n0 = (wv * 2 + nt) * 16 + col;
                bf16x8 bhiF = *(const bf16x8*)(h2hi + n0 * 128 + s * 32 + kg * 8);
                bf16x8 bloF = *(const bf16x8*)(h2lo + n0 * 128 + s * 32 + kg * 8);
                acc[nt] = __builtin_amdgcn_mfma_f32_16x16x32_bf16(ahi, bhiF, acc[nt], 0, 0, 0);
                acc[nt] = __builtin_amdgcn_mfma_f32_16x16x32_bf16(alo, bhiF, acc[nt], 0, 0, 0);
                acc[nt] = __builtin_amdgcn_mfma_f32_16x16x32_bf16(ahi, bloF, acc[nt], 0, 0, 0);
            }
        }
        __syncthreads();   // all A reads done before in-place writes
        #pragma unroll
        for (int nt = 0; nt < 2; ++nt) {
            int n = (wv * 2 + nt) * 16 + col;
            float bv = h2b[n];
            #pragma unroll
            for (int r = 0; r < 4; ++r)
                hL[(kg * 4 + r) * 132 + n] = fmaxf(acc[nt][r] + bv, 0.f);
        }
    }
    __syncthreads();

    // ---- phase H: h3; t<112: (row, j) ----
    if (t < 112) {
        int row = t / 7, j = t - row * 7;
        const float* rp = hL + row * 132;
        float a0 = h3b[j];
        const float* wr0 = h3w + j * 128;
        #pragma unroll 4
        for (int c = 0; c < 32; ++c) {
            float4 v = *(const float4*)(rp + c * 4);
            a0 += v.x * wr0[c * 4 + 0];
            a0 += v.y * wr0[c * 4 + 1];
            a0 += v.z * wr0[c * 4 + 2];
            a0 += v.w * wr0[c * 4 + 3];
        }
        out[(size_t)(b0 + row) * 7 + j] = a0;
    }
}

extern "C" void kernel_launch(void* const* d_in, const int* in_sizes, int n_in,
                              void* d_out, int out_size, void* d_ws, size_t ws_size,
                              hipStream_t stream) {
    const int*   frame = (const int*)d_in[0];
    const int*   ccol  = (const int*)d_in[1];
    const int*   cobj  = (const int*)d_in[2];
    const float* w1    = (const float*)d_in[3];
    const float* b1    = (const float*)d_in[4];
    const float* w2    = (const float*)d_in[5];
    const float* b2    = (const float*)d_in[6];
    const float* w3    = (const float*)d_in[7];
    const float* b3    = (const float*)d_in[8];
    const float* pw    = (const float*)d_in[9];
    const float* pb    = (const float*)d_in[10];
    const float* h1w   = (const float*)d_in[11];
    const float* h1b   = (const float*)d_in[12];
    const float* lng   = (const float*)d_in[13];
    const float* lnb   = (const float*)d_in[14];
    const float* h2w   = (const float*)d_in[15];
    const float* h2b   = (const float*)d_in[16];
    const float* h3w   = (const float*)d_in[17];
    const float* h3b   = (const float*)d_in[18];
    float* out = (float*)d_out;

    char* ws = (char*)d_ws;
    u16*   pwT      = (u16*)(ws + 0);                    // 77824 B
    u16*   w2r      = (u16*)(ws + 131072);               // 4096 B
    u16*   w3r      = (u16*)(ws + 139264);               // 16384 B
    u16*   h2hi     = (u16*)(ws + 163840);               // 32768 B
    u16*   h2lo     = (u16*)(ws + 196608);               // 32768 B
    u16*   h1hi     = (u16*)(ws + 229376);               // 40960 B
    u16*   h1lo     = (u16*)(ws + 270336);               // 40960 B
    u16*   w1hi     = (u16*)(ws + 311296);               // 1024 B
    u16*   w1lo     = (u16*)(ws + 312320);               // 1024 B

    k0_prep<<<340, 256, 0, stream>>>(pw, w2, w3, h2w, h1w, w1,
                                     pwT, w2r, w3r, h2hi, h2lo, h1hi, h1lo,
                                     w1hi, w1lo);
    kall<<<2048, 256, 0, stream>>>(frame, w1hi, w1lo, b1, w2r, b2,
                                   w3r, b3, ccol, cobj, pwT, pb,
                                   h1hi, h1lo, h1b, lng, lnb,
                                   h2hi, h2lo, h2b, h3w, h3b, out);
}